// Round 9
// baseline (134.811 us; speedup 1.0000x reference)
//
#include <hip/hip_runtime.h>

// SpatialIndependentDistribution, round 9: 8 waves/SIMD for latency hiding.
// R7 structure (LDS-staged pre-swizzled f16 fragments, chained MFMA 16x16x16,
// quad-parallel epilogue) but 32 pixels/wave (2 chains) x 8192 waves:
// 1024 blocks x 512 threads -> 4 blocks/CU x 8 waves = 32 waves/CU fully
// resident (2x the TLP of R7's 4 waves/SIMD; LDS 100 KB/CU of 160).

#define NEG_HALF_LOG_2PI -0.91893853320467274f

typedef _Float16 f16x4 __attribute__((ext_vector_type(4)));
typedef __fp16   hf2   __attribute__((ext_vector_type(2)));
typedef float    f32x4 __attribute__((ext_vector_type(4)));

__device__ inline f16x4 pack_f16(f32x4 v) {
    hf2 p0 = __builtin_amdgcn_cvt_pkrtz(v[0], v[1]);
    hf2 p1 = __builtin_amdgcn_cvt_pkrtz(v[2], v[3]);
    f16x4 r;
    __builtin_memcpy(&r, &p0, 4);
    __builtin_memcpy((char*)&r + 4, &p1, 4);
    return r;
}

__device__ inline f16x4 relu_pack(f32x4 d) {
    hf2 p0 = __builtin_amdgcn_cvt_pkrtz(fmaxf(d[0], 0.0f), fmaxf(d[1], 0.0f));
    hf2 p1 = __builtin_amdgcn_cvt_pkrtz(fmaxf(d[2], 0.0f), fmaxf(d[3], 0.0f));
    f16x4 r;
    __builtin_memcpy(&r, &p0, 4);
    __builtin_memcpy((char*)&r + 4, &p1, 4);
    return r;
}

__global__ __launch_bounds__(512, 8) void spatial_main(
    const float* __restrict__ samples,   // [64,16,64,64]
    const float* __restrict__ n1_b1,     // [16]
    const float* __restrict__ n1_w2,     // [16,16]
    const float* __restrict__ n1_b2,     // [16]
    const float* __restrict__ n1_w3,     // [2,16]
    const float* __restrict__ n1_b3,     // [2]
    const float* __restrict__ w1,        // [15,16,16] zero-padded triangular
    const float* __restrict__ b1,        // [15,16]
    const float* __restrict__ w2,        // [15,16,16]
    const float* __restrict__ b2,        // [15,16]
    const float* __restrict__ w3,        // [15,2,16]
    const float* __restrict__ b3,        // [15,2]
    float* __restrict__ out)             // [64,64,64]
{
    // A-fragments: fA[sl*256 + lane*4 + i] = W_sl[lane&15][4*(lane>>4)+i], f16
    __shared__ _Float16 fA[45 * 256];    // 23040 B
    __shared__ float    fC[15 * 2 * 16]; // 1920 B  (b1,b2 as MFMA C operands)

    const int tid   = threadIdx.x;
    const int lane  = tid & 63;
    const int wv    = tid >> 6;           // 0..7
    const int q     = lane >> 4;          // quad 0..3
    const int col   = lane & 15;
    const int lane4 = lane << 2;
    const int q4    = q << 2;
    const int roff  = col * 16 + q4;      // head A-frag: [row][4q], contiguous

    // ---- stage w1/w2 fragments: 30 matrices x 64 float4, coalesced ----
    for (int j = tid; j < 30 * 64; j += 512) {
        int m   = j >> 6;                 // matrix 0..29
        int rem = j & 63;
        int r   = rem >> 2;               // row 0..15
        int c   = rem & 3;                // float4 within row
        const float* src = (m < 15) ? (w1 + m * 256) : (w2 + (m - 15) * 256);
        f32x4 v = *(const f32x4*)(src + r * 16 + (c << 2));
        int sl = (m < 15) ? (m * 3) : ((m - 15) * 3 + 1);
        *(f16x4*)&fA[sl * 256 + (((c << 4) + r) << 2)] = pack_f16(v);
    }
    // ---- stage w3 fragments (rows replicated into {0,1} mod 4, else 0) ----
    for (int j = tid; j < 15 * 64; j += 512) {
        int s  = j >> 6;
        int ln = j & 63;
        int r  = ln & 15;
        int qq = ln >> 4;
        f32x4 v = {0.f, 0.f, 0.f, 0.f};
        if ((r & 3) < 2) v = *(const f32x4*)(w3 + s * 32 + ((r & 1) << 4) + (qq << 2));
        *(f16x4*)&fA[(s * 3 + 2) * 256 + (ln << 2)] = pack_f16(v);
    }
    // ---- stage b1/b2 (480 entries, stride loop) ----
    for (int j = tid; j < 15 * 2 * 16; j += 512) {
        int s = j >> 5, layer = (j >> 4) & 1, o = j & 15;
        fC[j] = layer ? b2[s * 16 + o] : b1[s * 16 + o];
    }

    // ---- pixel loads + head (independent of LDS, overlaps staging) ----
    const int pbase = blockIdx.x * 256 + wv * 32;       // wave's first pixel
    const int b     = pbase >> 12;
    const int hw    = pbase & 4095;
    const float* xw = samples + ((size_t)b << 16) + hw; // + ch*4096 + 0..31

    // 2 chains of 16 pixels; lane's epilogue pixel = ((q&1)<<4) + col
    const int c01  = q & 1;
    const int ppix = (c01 << 4) + col;

    f16x4 bx[2];
    #pragma unroll
    for (int ch = 0; ch < 2; ++ch)
        #pragma unroll
        for (int i = 0; i < 4; ++i)
            bx[ch][i] = (_Float16)xw[((q4 + i) << 12) + (ch << 4) + col];

    float accz, accl;
    {   // head: n1 net on zero input; B operand pixel-independent; 2 MFMAs
        f32x4 c1h = *(const f32x4*)(n1_b1 + q4);        // C-layout == B-layout
        f16x4 h1h = relu_pack(c1h);
        f16x4 a2h = pack_f16(*(const f32x4*)(n1_w2 + roff));
        f32x4 c2h = *(const f32x4*)(n1_b2 + q4);
        f32x4 d2h = __builtin_amdgcn_mfma_f32_16x16x16f16(a2h, h1h, c2h, 0, 0, 0);
        f16x4 h2h = relu_pack(d2h);
        f32x4 v3h = {0.f, 0.f, 0.f, 0.f};
        if ((col & 3) < 2) v3h = *(const f32x4*)(n1_w3 + ((col & 1) << 4) + q4);
        f16x4 a3h = pack_f16(v3h);
        f32x4 c3h = {n1_b3[0], n1_b3[1], 0.0f, 0.0f};
        f32x4 d3h = __builtin_amdgcn_mfma_f32_16x16x16f16(a3h, h2h, c3h, 0, 0, 0);
        float x0 = xw[ppix];
        float ls = d3h[1];
        float z0 = (x0 - d3h[0]) * __expf(-ls);
        accz = z0 * z0;
        accl = ls;
    }

    __syncthreads();

    // ---- 15 autoregressive steps, frags from LDS ----
    #pragma unroll
    for (int s = 0; s < 15; ++s) {
        f16x4 a1 = *(const f16x4*)&fA[(s * 3 + 0) * 256 + lane4];  // ds_read_b64
        f16x4 a2 = *(const f16x4*)&fA[(s * 3 + 1) * 256 + lane4];
        f16x4 a3 = *(const f16x4*)&fA[(s * 3 + 2) * 256 + lane4];
        f32x4 c1 = *(const f32x4*)&fC[(s * 2 + 0) * 16 + q4];
        f32x4 c2 = *(const f32x4*)&fC[(s * 2 + 1) * 16 + q4];
        f32x4 c3 = {b3[s * 2 + 0], b3[s * 2 + 1], 0.0f, 0.0f};     // s_load

        float loc_q[2], ls_q[2];
        #pragma unroll
        for (int ch = 0; ch < 2; ++ch) {
            f32x4 d1 = __builtin_amdgcn_mfma_f32_16x16x16f16(a1, bx[ch], c1, 0, 0, 0);
            f16x4 h1 = relu_pack(d1);
            f32x4 d2 = __builtin_amdgcn_mfma_f32_16x16x16f16(a2, h1, c2, 0, 0, 0);
            f16x4 h2 = relu_pack(d2);
            f32x4 d3 = __builtin_amdgcn_mfma_f32_16x16x16f16(a3, h2, c3, 0, 0, 0);
            loc_q[ch] = d3[0];
            ls_q[ch]  = d3[1];
        }
        // quads {0,2} take chain 0, {1,3} chain 1 -> 1 cndmask each
        float loc = c01 ? loc_q[1] : loc_q[0];
        float ls  = c01 ? ls_q[1]  : ls_q[0];
        float xn  = xw[((s + 1) << 12) + ppix];      // channel s+1
        float z   = (xn - loc) * __expf(-ls);
        accz = fmaf(z, z, accz);
        accl += ls;
    }

    // out = -0.5*accz - accl + 16*(-0.5*log(2pi)); quads 0,1 write (2,3 are dups)
    if (q < 2)
        out[pbase + ppix] = fmaf(-0.5f, accz, 16.0f * NEG_HALF_LOG_2PI - accl);
}

extern "C" void kernel_launch(void* const* d_in, const int* in_sizes, int n_in,
                              void* d_out, int out_size, void* d_ws, size_t ws_size,
                              hipStream_t stream) {
    const float* samples = (const float*)d_in[0];
    // d_in[1] = n1_w1 unused (first-channel input is zeros)
    const float* n1_b1   = (const float*)d_in[2];
    const float* n1_w2   = (const float*)d_in[3];
    const float* n1_b2   = (const float*)d_in[4];
    const float* n1_w3   = (const float*)d_in[5];
    const float* n1_b3   = (const float*)d_in[6];
    const float* w1      = (const float*)d_in[7];
    const float* b1      = (const float*)d_in[8];
    const float* w2      = (const float*)d_in[9];
    const float* b2      = (const float*)d_in[10];
    const float* w3      = (const float*)d_in[11];
    const float* b3      = (const float*)d_in[12];
    float* out = (float*)d_out;

    // 262144 pixels / 32 per wave / 8 waves per block = 1024 blocks
    spatial_main<<<dim3(1024), dim3(512), 0, stream>>>(
        samples, n1_b1, n1_w2, n1_b2, n1_w3, n1_b3,
        w1, b1, w2, b2, w3, b3, out);
}

// Round 10
// 104.708 us; speedup vs baseline: 1.2875x; 1.2875x over previous
//
#include <hip/hip_runtime.h>

// SpatialIndependentDistribution, round 10.
// R7 structure + three fixes from R9's spill/conflict evidence:
//  1) all 16 channels of the lane's own pixel preloaded to fp32 regs -> no
//     global loads inside the 15-step loop (kills per-step L1-latency tail)
//  2) destination-ordered LDS staging (conflict-free b64 writes; fA grouped
//     [w1|w2|w3] so the matrix index is wave-uniform per staging iteration)
//  3) 256 thr, 4 chains, __launch_bounds__(256,4): 128 VGPR cap, no spill.

#define NEG_HALF_LOG_2PI -0.91893853320467274f

typedef _Float16 f16x4 __attribute__((ext_vector_type(4)));
typedef __fp16   hf2   __attribute__((ext_vector_type(2)));
typedef float    f32x4 __attribute__((ext_vector_type(4)));

__device__ inline f16x4 pack_f16(f32x4 v) {
    hf2 p0 = __builtin_amdgcn_cvt_pkrtz(v[0], v[1]);
    hf2 p1 = __builtin_amdgcn_cvt_pkrtz(v[2], v[3]);
    f16x4 r;
    __builtin_memcpy(&r, &p0, 4);
    __builtin_memcpy((char*)&r + 4, &p1, 4);
    return r;
}

__device__ inline f16x4 relu_pack(f32x4 d) {
    hf2 p0 = __builtin_amdgcn_cvt_pkrtz(fmaxf(d[0], 0.0f), fmaxf(d[1], 0.0f));
    hf2 p1 = __builtin_amdgcn_cvt_pkrtz(fmaxf(d[2], 0.0f), fmaxf(d[3], 0.0f));
    f16x4 r;
    __builtin_memcpy(&r, &p0, 4);
    __builtin_memcpy((char*)&r + 4, &p1, 4);
    return r;
}

__global__ __launch_bounds__(256, 4) void spatial_main(
    const float* __restrict__ samples,   // [64,16,64,64]
    const float* __restrict__ n1_b1,     // [16]
    const float* __restrict__ n1_w2,     // [16,16]
    const float* __restrict__ n1_b2,     // [16]
    const float* __restrict__ n1_w3,     // [2,16]
    const float* __restrict__ n1_b3,     // [2]
    const float* __restrict__ w1,        // [15,16,16] zero-padded triangular
    const float* __restrict__ b1,        // [15,16]
    const float* __restrict__ w2,        // [15,16,16]
    const float* __restrict__ b2,        // [15,16]
    const float* __restrict__ w3,        // [15,2,16]
    const float* __restrict__ b3,        // [15,2]
    float* __restrict__ out)             // [64,64,64]
{
    // fA grouped by layer: m = s (w1), 15+s (w2), 30+s (w3)
    // fA[m*256 + lane*4 + i] = W_m[lane&15][4*(lane>>4)+i]  (f16)
    __shared__ _Float16 fA[45 * 256];    // 23040 B
    __shared__ float    fC[15 * 2 * 16]; // 1920 B  (b1,b2 as MFMA C operands)

    const int tid   = threadIdx.x;
    const int lane  = tid & 63;
    const int wv    = tid >> 6;
    const int q     = lane >> 4;          // quad 0..3
    const int col   = lane & 15;
    const int lane4 = lane << 2;
    const int q4    = q << 2;
    const int roff  = col * 16 + q4;      // head A-frag: [row][4q], contiguous

    // ---- stage fA, destination-ordered: one matrix per wave-iteration ----
    // j = it*256 + tid; m = j>>6 is wave-uniform; lane ln stages
    // dest fA[m*256 + ln*4 ..+3]  <-  W_m[ln&15][(ln>>4)*4 ..+3]
    for (int j = tid; j < 45 * 64; j += 256) {
        int m  = j >> 6;                  // wave-uniform matrix id 0..44
        int ln = j & 63;
        int r  = ln & 15;
        int c  = ln >> 4;                 // k-group 0..3
        f32x4 v;
        if (m < 15) {
            v = *(const f32x4*)(w1 + m * 256 + r * 16 + (c << 2));
        } else if (m < 30) {
            v = *(const f32x4*)(w2 + (m - 15) * 256 + r * 16 + (c << 2));
        } else {
            v = (f32x4){0.f, 0.f, 0.f, 0.f};
            if ((r & 3) < 2)              // replicate W3 rows into {0,1} mod 4
                v = *(const f32x4*)(w3 + (m - 30) * 32 + ((r & 1) << 4) + (c << 2));
        }
        *(f16x4*)&fA[(j << 2)] = pack_f16(v);   // lane-consecutive b64 writes
    }
    // ---- stage b1/b2 (480 entries, stride loop) ----
    for (int j = tid; j < 15 * 2 * 16; j += 256) {
        int s = j >> 5, layer = (j >> 4) & 1, o = j & 15;
        fC[j] = layer ? b2[s * 16 + o] : b1[s * 16 + o];
    }

    // ---- pixel loads (overlap staging): own pixel fp32 + B-fragments f16 ----
    const int pbase = blockIdx.x * 256 + wv * 64;       // wave's first pixel
    const int b     = pbase >> 12;
    const int hw    = pbase & 4095;
    const float* xw = samples + ((size_t)b << 16) + hw; // + ch*4096 + 0..63

    // all 16 channels of the lane's own pixel (pbase+lane), coalesced
    float px[16];
    #pragma unroll
    for (int c = 0; c < 16; ++c) px[c] = xw[(c << 12) + lane];

    // B-fragments: chain ch covers pixels pbase+16ch..+15; lane holds ch 4q..4q+3
    f16x4 bx[4];
    #pragma unroll
    for (int ch = 0; ch < 4; ++ch)
        #pragma unroll
        for (int i = 0; i < 4; ++i)
            bx[ch][i] = (_Float16)xw[((q4 + i) << 12) + (ch << 4) + col];

    float accz, accl;
    {   // head: n1 net on zero input; B operand pixel-independent; 2 MFMAs
        f32x4 c1h = *(const f32x4*)(n1_b1 + q4);        // C-layout == B-layout
        f16x4 h1h = relu_pack(c1h);
        f16x4 a2h = pack_f16(*(const f32x4*)(n1_w2 + roff));
        f32x4 c2h = *(const f32x4*)(n1_b2 + q4);
        f32x4 d2h = __builtin_amdgcn_mfma_f32_16x16x16f16(a2h, h1h, c2h, 0, 0, 0);
        f16x4 h2h = relu_pack(d2h);
        f32x4 v3h = {0.f, 0.f, 0.f, 0.f};
        if ((col & 3) < 2) v3h = *(const f32x4*)(n1_w3 + ((col & 1) << 4) + q4);
        f16x4 a3h = pack_f16(v3h);
        f32x4 c3h = {n1_b3[0], n1_b3[1], 0.0f, 0.0f};
        f32x4 d3h = __builtin_amdgcn_mfma_f32_16x16x16f16(a3h, h2h, c3h, 0, 0, 0);
        float ls = d3h[1];
        float z0 = (px[0] - d3h[0]) * __expf(-ls);
        accz = z0 * z0;
        accl = ls;
    }

    __syncthreads();

    // ---- 15 autoregressive steps; NO global loads in the loop ----
    #pragma unroll
    for (int s = 0; s < 15; ++s) {
        f16x4 a1 = *(const f16x4*)&fA[(s)      * 256 + lane4];   // ds_read_b64
        f16x4 a2 = *(const f16x4*)&fA[(15 + s) * 256 + lane4];
        f16x4 a3 = *(const f16x4*)&fA[(30 + s) * 256 + lane4];
        f32x4 c1 = *(const f32x4*)&fC[(s * 2 + 0) * 16 + q4];
        f32x4 c2 = *(const f32x4*)&fC[(s * 2 + 1) * 16 + q4];
        f32x4 c3 = {b3[s * 2 + 0], b3[s * 2 + 1], 0.0f, 0.0f};   // s_load

        float loc_q[4], ls_q[4];
        #pragma unroll
        for (int ch = 0; ch < 4; ++ch) {
            f32x4 d1 = __builtin_amdgcn_mfma_f32_16x16x16f16(a1, bx[ch], c1, 0, 0, 0);
            f16x4 h1 = relu_pack(d1);
            f32x4 d2 = __builtin_amdgcn_mfma_f32_16x16x16f16(a2, h1, c2, 0, 0, 0);
            f16x4 h2 = relu_pack(d2);
            f32x4 d3 = __builtin_amdgcn_mfma_f32_16x16x16f16(a3, h2, c3, 0, 0, 0);
            loc_q[ch] = d3[0];
            ls_q[ch]  = d3[1];
        }
        // quad q takes chain q's epilogue; target sample from registers
        float loc = q == 0 ? loc_q[0] : q == 1 ? loc_q[1] : q == 2 ? loc_q[2] : loc_q[3];
        float ls  = q == 0 ? ls_q[0]  : q == 1 ? ls_q[1]  : q == 2 ? ls_q[2]  : ls_q[3];
        float z   = (px[s + 1] - loc) * __expf(-ls);
        accz = fmaf(z, z, accz);
        accl += ls;
    }

    // out = -0.5*accz - accl + 16*(-0.5*log(2pi)); all 64 lanes write coalesced
    out[pbase + lane] = fmaf(-0.5f, accz, 16.0f * NEG_HALF_LOG_2PI - accl);
}

extern "C" void kernel_launch(void* const* d_in, const int* in_sizes, int n_in,
                              void* d_out, int out_size, void* d_ws, size_t ws_size,
                              hipStream_t stream) {
    const float* samples = (const float*)d_in[0];
    // d_in[1] = n1_w1 unused (first-channel input is zeros)
    const float* n1_b1   = (const float*)d_in[2];
    const float* n1_w2   = (const float*)d_in[3];
    const float* n1_b2   = (const float*)d_in[4];
    const float* n1_w3   = (const float*)d_in[5];
    const float* n1_b3   = (const float*)d_in[6];
    const float* w1      = (const float*)d_in[7];
    const float* b1      = (const float*)d_in[8];
    const float* w2      = (const float*)d_in[9];
    const float* b2      = (const float*)d_in[10];
    const float* w3      = (const float*)d_in[11];
    const float* b3      = (const float*)d_in[12];
    float* out = (float*)d_out;

    // 262144 pixels / 64 per wave / 4 waves per block = 1024 blocks
    spatial_main<<<dim3(1024), dim3(256), 0, stream>>>(
        samples, n1_b1, n1_w2, n1_b2, n1_w3, n1_b3,
        w1, b1, w2, b2, w3, b3, out);
}